// Round 1
// baseline (2959.997 us; speedup 1.0000x reference)
//
#include <hip/hip_runtime.h>

#define N_NODES 100000
#define N_EDGES 1600000
#define D 128

// ---------------- scatter: aggr[dst] += x[src] ----------------
// one 32-thread group per edge, float4 per thread (4 channels)
__global__ __launch_bounds__(256) void scatter_kernel(const float* __restrict__ x,
                                                      const int* __restrict__ ei,
                                                      float* __restrict__ aggr) {
    unsigned tid = blockIdx.x * 256u + threadIdx.x;
    unsigned e = tid >> 5;
    unsigned g = tid & 31u;
    if (e >= N_EDGES) return;
    int src = ei[e];
    int dst = ei[N_EDGES + e];
    const float4 v = *(const float4*)(x + (size_t)src * D + g * 4);
    float* a = aggr + (size_t)dst * D + g * 4;
    unsafeAtomicAdd(a + 0, v.x);
    unsafeAtomicAdd(a + 1, v.y);
    unsafeAtomicAdd(a + 2, v.z);
    unsafeAtomicAdd(a + 3, v.w);
}

// ---------------- GEMM: out = aggr@W_rel + x@W_root + b_rel ----------------
// f32 vector GEMM (no fp32 MFMA on CDNA4). Block tile 128 rows x 128 cols,
// BK=16, 256 threads, 8x8 micro-tile per thread.
// A staged transposed As[k][row] (stride 132: 16B-aligned, breaks conflicts),
// W staged row-major Ws[k][col].
__global__ __launch_bounds__(256) void gemm_kernel(const float* __restrict__ aggr,
                                                   const float* __restrict__ x,
                                                   const float* __restrict__ Wrel,
                                                   const float* __restrict__ Wroot,
                                                   const float* __restrict__ brel,
                                                   float* __restrict__ out) {
    __shared__ float As[16][132];
    __shared__ float Ws[16][132];
    const int t = threadIdx.x;
    const int rg = t >> 4;   // 0..15 -> rows rg*8..+7
    const int cg = t & 15;   // 0..15 -> cols {4cg..+3} and {64+4cg..+3}
    const int blockRow = blockIdx.x * 128;

    float acc[8][8];
#pragma unroll
    for (int i = 0; i < 8; ++i)
#pragma unroll
        for (int j = 0; j < 8; ++j) acc[i][j] = 0.0f;

    for (int kt = 0; kt < 16; ++kt) {
        const float* Ab;
        const float* Wb;
        if (kt < 8) { Ab = aggr + kt * 16;       Wb = Wrel + kt * 16 * D; }
        else        { Ab = x + (kt - 8) * 16;    Wb = Wroot + (kt - 8) * 16 * D; }

        // stage A tile: 128 rows x 16 k, transposed into As[k][row]
#pragma unroll
        for (int s = t; s < 512; s += 256) {
            int row = s >> 2;
            int q = (s & 3) * 4;
            int grow = blockRow + row;
            float4 v = make_float4(0.f, 0.f, 0.f, 0.f);
            if (grow < N_NODES) v = *(const float4*)(Ab + (size_t)grow * D + q);
            As[q + 0][row] = v.x;
            As[q + 1][row] = v.y;
            As[q + 2][row] = v.z;
            As[q + 3][row] = v.w;
        }
        // stage W tile: 16 k x 128 cols
#pragma unroll
        for (int s = t; s < 512; s += 256) {
            int k = s >> 5;
            int cq = (s & 31) * 4;
            *(float4*)&Ws[k][cq] = *(const float4*)(Wb + k * D + cq);
        }
        __syncthreads();

#pragma unroll
        for (int k = 0; k < 16; ++k) {
            float4 a0 = *(float4*)&As[k][rg * 8];
            float4 a1 = *(float4*)&As[k][rg * 8 + 4];
            float4 w0 = *(float4*)&Ws[k][cg * 4];
            float4 w1 = *(float4*)&Ws[k][64 + cg * 4];
            float av[8] = {a0.x, a0.y, a0.z, a0.w, a1.x, a1.y, a1.z, a1.w};
            float wv[8] = {w0.x, w0.y, w0.z, w0.w, w1.x, w1.y, w1.z, w1.w};
#pragma unroll
            for (int i = 0; i < 8; ++i)
#pragma unroll
                for (int j = 0; j < 8; ++j) acc[i][j] += av[i] * wv[j];
        }
        __syncthreads();
    }

    // epilogue: += b_rel, write h to out
    float4 b0 = *(const float4*)(brel + cg * 4);
    float4 b1 = *(const float4*)(brel + 64 + cg * 4);
#pragma unroll
    for (int i = 0; i < 8; ++i) {
        int row = blockRow + rg * 8 + i;
        if (row < N_NODES) {
            float4 o0 = make_float4(acc[i][0] + b0.x, acc[i][1] + b0.y,
                                    acc[i][2] + b0.z, acc[i][3] + b0.w);
            float4 o1 = make_float4(acc[i][4] + b1.x, acc[i][5] + b1.y,
                                    acc[i][6] + b1.z, acc[i][7] + b1.w);
            *(float4*)(out + (size_t)row * D + cg * 4) = o0;
            *(float4*)(out + (size_t)row * D + 64 + cg * 4) = o1;
        }
    }
}

// ---------------- BN stats: per-channel sum / sumsq ----------------
__global__ __launch_bounds__(256) void stats_kernel(const float* __restrict__ h,
                                                    float* __restrict__ gsum,
                                                    float* __restrict__ gss) {
    const int t = threadIdx.x;
    const int c = t & 127;
    const int half = t >> 7;
    const size_t base = (size_t)blockIdx.x * 392;
    float s = 0.f, ss = 0.f;
    for (int i = 0; i < 196; ++i) {
        size_t row = base + 2 * i + half;
        if (row < N_NODES) {
            float v = h[row * D + c];
            s += v;
            ss += v * v;
        }
    }
    __shared__ float red[256];
    red[t] = s;
    __syncthreads();
    float s2 = 0.f;
    if (t < 128) s2 = red[t] + red[t + 128];
    __syncthreads();
    red[t] = ss;
    __syncthreads();
    if (t < 128) {
        float ss2 = red[t] + red[t + 128];
        unsafeAtomicAdd(&gsum[t], s2);
        unsafeAtomicAdd(&gss[t], ss2);
    }
}

// ---------------- finalize: scale/shift per channel ----------------
__global__ void finalize_kernel(const float* __restrict__ gsum,
                                const float* __restrict__ gss,
                                const float* __restrict__ gamma,
                                const float* __restrict__ beta,
                                float* __restrict__ scale,
                                float* __restrict__ shift) {
    int c = threadIdx.x;
    const float inv_n = 1.0f / (float)N_NODES;
    float mean = gsum[c] * inv_n;
    float var = gss[c] * inv_n - mean * mean;
    float rs = rsqrtf(var + 1e-5f);
    float sc = gamma[c] * rs;
    scale[c] = sc;
    shift[c] = beta[c] - mean * sc;
}

// ---------------- normalize + relu, in place ----------------
__global__ __launch_bounds__(256) void norm_kernel(float* __restrict__ h,
                                                   const float* __restrict__ scale,
                                                   const float* __restrict__ shift) {
    size_t tid = (size_t)blockIdx.x * 256 + threadIdx.x;
    size_t e = tid * 4;
    if (e >= (size_t)N_NODES * D) return;
    int c = (int)(e & 127);
    float4 v = *(float4*)(h + e);
    v.x = fmaxf(v.x * scale[c + 0] + shift[c + 0], 0.f);
    v.y = fmaxf(v.y * scale[c + 1] + shift[c + 1], 0.f);
    v.z = fmaxf(v.z * scale[c + 2] + shift[c + 2], 0.f);
    v.w = fmaxf(v.w * scale[c + 3] + shift[c + 3], 0.f);
    *(float4*)(h + e) = v;
}

extern "C" void kernel_launch(void* const* d_in, const int* in_sizes, int n_in,
                              void* d_out, int out_size, void* d_ws, size_t ws_size,
                              hipStream_t stream) {
    const float* x     = (const float*)d_in[0];
    const int*   ei    = (const int*)d_in[1];
    const float* Wroot = (const float*)d_in[2];
    const float* Wrel  = (const float*)d_in[3];
    const float* brel  = (const float*)d_in[4];
    const float* gamma = (const float*)d_in[5];
    const float* beta  = (const float*)d_in[6];
    float* out = (float*)d_out;

    float* aggr  = (float*)d_ws;
    float* gsum  = aggr + (size_t)N_NODES * D;
    float* gss   = gsum + 128;
    float* scale = gss + 128;
    float* shift = scale + 128;

    // zero aggr + stats (ws is poisoned 0xAA before every call)
    hipMemsetAsync(d_ws, 0, ((size_t)N_NODES * D + 256) * sizeof(float), stream);

    scatter_kernel<<<(N_EDGES * 32) / 256, 256, 0, stream>>>(x, ei, aggr);
    gemm_kernel<<<(N_NODES + 127) / 128, 256, 0, stream>>>(aggr, x, Wrel, Wroot, brel, out);
    stats_kernel<<<256, 256, 0, stream>>>(out, gsum, gss);
    finalize_kernel<<<1, 128, 0, stream>>>(gsum, gss, gamma, beta, scale, shift);
    norm_kernel<<<12500, 256, 0, stream>>>(out, scale, shift);
}

// Round 2
// 601.645 us; speedup vs baseline: 4.9198x; 4.9198x over previous
//
#include <hip/hip_runtime.h>

#define N_NODES 100000
#define N_EDGES 1600000
#define D 128
#define SCAN_BLOCKS 392                  // 392*256 = 100352 >= N_NODES+1
#define SCAN_TOT (SCAN_BLOCKS * 256)

// ---------------- CSR build: histogram over dst ----------------
__global__ __launch_bounds__(256) void hist_kernel(const int* __restrict__ ei,
                                                   int* __restrict__ count) {
    int e = blockIdx.x * 256 + threadIdx.x;
    if (e < N_EDGES) atomicAdd(&count[ei[N_EDGES + e]], 1);
}

// ---------------- scan step 1: per-block sums ----------------
__global__ __launch_bounds__(256) void scan_partial(const int* __restrict__ count,
                                                    int* __restrict__ bsum) {
    int t = threadIdx.x;
    int i = blockIdx.x * 256 + t;
    __shared__ int red[256];
    red[t] = count[i];
    __syncthreads();
    for (int off = 128; off > 0; off >>= 1) {
        if (t < off) red[t] += red[t + off];
        __syncthreads();
    }
    if (t == 0) bsum[blockIdx.x] = red[0];
}

// ---------------- scan step 2: exclusive scan of block sums ----------------
__global__ void scan_bsum(int* __restrict__ bsum) {
    if (threadIdx.x == 0) {
        int run = 0;
        for (int b = 0; b < SCAN_BLOCKS; ++b) {
            int v = bsum[b];
            bsum[b] = run;
            run += v;
        }
    }
}

// ---------------- scan step 3: block-local exclusive scan + offset ----------------
__global__ __launch_bounds__(256) void scan_final(const int* __restrict__ count,
                                                  const int* __restrict__ bsum,
                                                  int* __restrict__ rowstart,
                                                  int* __restrict__ cursor) {
    int t = threadIdx.x;
    int i = blockIdx.x * 256 + t;
    __shared__ int red[256];
    int v = count[i];
    red[t] = v;
    __syncthreads();
    for (int off = 1; off < 256; off <<= 1) {
        int a = (t >= off) ? red[t - off] : 0;
        __syncthreads();
        red[t] += a;
        __syncthreads();
    }
    int excl = red[t] - v + bsum[blockIdx.x];
    if (i <= N_NODES) rowstart[i] = excl;
    if (i < N_NODES) cursor[i] = excl;
}

// ---------------- bucket fill: srcs sorted by dst ----------------
__global__ __launch_bounds__(256) void bucket_kernel(const int* __restrict__ ei,
                                                     int* __restrict__ cursor,
                                                     int* __restrict__ srcs) {
    int e = blockIdx.x * 256 + threadIdx.x;
    if (e < N_EDGES) {
        int dst = ei[N_EDGES + e];
        int src = ei[e];
        int pos = atomicAdd(&cursor[dst], 1);
        srcs[pos] = src;
    }
}

// ---------------- gather: aggr[n] = sum_{e in CSR[n]} x[srcs[e]] ----------------
// 64 lanes per node (float2 per lane), 4 nodes per 256-thread block
__global__ __launch_bounds__(256) void gather_kernel(const float* __restrict__ x,
                                                     const int* __restrict__ rowstart,
                                                     const int* __restrict__ srcs,
                                                     float* __restrict__ aggr) {
    int t = threadIdx.x;
    int node = blockIdx.x * 4 + (t >> 6);
    int lane = t & 63;
    int begin = rowstart[node];
    int end = rowstart[node + 1];
    const float* xp = x + lane * 2;
    float2 acc = make_float2(0.f, 0.f);
    int e = begin;
    for (; e + 1 < end; e += 2) {
        int s0 = srcs[e];
        int s1 = srcs[e + 1];
        float2 v0 = *(const float2*)(xp + (size_t)s0 * D);
        float2 v1 = *(const float2*)(xp + (size_t)s1 * D);
        acc.x += v0.x + v1.x;
        acc.y += v0.y + v1.y;
    }
    if (e < end) {
        int s = srcs[e];
        float2 v = *(const float2*)(xp + (size_t)s * D);
        acc.x += v.x;
        acc.y += v.y;
    }
    *(float2*)(aggr + (size_t)node * D + lane * 2) = acc;
}

// ---------------- GEMM: out = aggr@W_rel + x@W_root + b_rel ----------------
__global__ __launch_bounds__(256) void gemm_kernel(const float* __restrict__ aggr,
                                                   const float* __restrict__ x,
                                                   const float* __restrict__ Wrel,
                                                   const float* __restrict__ Wroot,
                                                   const float* __restrict__ brel,
                                                   float* __restrict__ out) {
    __shared__ float As[16][132];
    __shared__ float Ws[16][132];
    const int t = threadIdx.x;
    const int rg = t >> 4;
    const int cg = t & 15;
    const int blockRow = blockIdx.x * 128;

    float acc[8][8];
#pragma unroll
    for (int i = 0; i < 8; ++i)
#pragma unroll
        for (int j = 0; j < 8; ++j) acc[i][j] = 0.0f;

    for (int kt = 0; kt < 16; ++kt) {
        const float* Ab;
        const float* Wb;
        if (kt < 8) { Ab = aggr + kt * 16;       Wb = Wrel + kt * 16 * D; }
        else        { Ab = x + (kt - 8) * 16;    Wb = Wroot + (kt - 8) * 16 * D; }

#pragma unroll
        for (int s = t; s < 512; s += 256) {
            int row = s >> 2;
            int q = (s & 3) * 4;
            int grow = blockRow + row;
            float4 v = make_float4(0.f, 0.f, 0.f, 0.f);
            if (grow < N_NODES) v = *(const float4*)(Ab + (size_t)grow * D + q);
            As[q + 0][row] = v.x;
            As[q + 1][row] = v.y;
            As[q + 2][row] = v.z;
            As[q + 3][row] = v.w;
        }
#pragma unroll
        for (int s = t; s < 512; s += 256) {
            int k = s >> 5;
            int cq = (s & 31) * 4;
            *(float4*)&Ws[k][cq] = *(const float4*)(Wb + k * D + cq);
        }
        __syncthreads();

#pragma unroll
        for (int k = 0; k < 16; ++k) {
            float4 a0 = *(float4*)&As[k][rg * 8];
            float4 a1 = *(float4*)&As[k][rg * 8 + 4];
            float4 w0 = *(float4*)&Ws[k][cg * 4];
            float4 w1 = *(float4*)&Ws[k][64 + cg * 4];
            float av[8] = {a0.x, a0.y, a0.z, a0.w, a1.x, a1.y, a1.z, a1.w};
            float wv[8] = {w0.x, w0.y, w0.z, w0.w, w1.x, w1.y, w1.z, w1.w};
#pragma unroll
            for (int i = 0; i < 8; ++i)
#pragma unroll
                for (int j = 0; j < 8; ++j) acc[i][j] += av[i] * wv[j];
        }
        __syncthreads();
    }

    float4 b0 = *(const float4*)(brel + cg * 4);
    float4 b1 = *(const float4*)(brel + 64 + cg * 4);
#pragma unroll
    for (int i = 0; i < 8; ++i) {
        int row = blockRow + rg * 8 + i;
        if (row < N_NODES) {
            float4 o0 = make_float4(acc[i][0] + b0.x, acc[i][1] + b0.y,
                                    acc[i][2] + b0.z, acc[i][3] + b0.w);
            float4 o1 = make_float4(acc[i][4] + b1.x, acc[i][5] + b1.y,
                                    acc[i][6] + b1.z, acc[i][7] + b1.w);
            *(float4*)(out + (size_t)row * D + cg * 4) = o0;
            *(float4*)(out + (size_t)row * D + 64 + cg * 4) = o1;
        }
    }
}

// ---------------- BN stats ----------------
__global__ __launch_bounds__(256) void stats_kernel(const float* __restrict__ h,
                                                    float* __restrict__ gsum,
                                                    float* __restrict__ gss) {
    const int t = threadIdx.x;
    const int c = t & 127;
    const int half = t >> 7;
    const size_t base = (size_t)blockIdx.x * 392;
    float s = 0.f, ss = 0.f;
    for (int i = 0; i < 196; ++i) {
        size_t row = base + 2 * i + half;
        if (row < N_NODES) {
            float v = h[row * D + c];
            s += v;
            ss += v * v;
        }
    }
    __shared__ float red[256];
    red[t] = s;
    __syncthreads();
    float s2 = 0.f;
    if (t < 128) s2 = red[t] + red[t + 128];
    __syncthreads();
    red[t] = ss;
    __syncthreads();
    if (t < 128) {
        float ss2 = red[t] + red[t + 128];
        unsafeAtomicAdd(&gsum[t], s2);
        unsafeAtomicAdd(&gss[t], ss2);
    }
}

__global__ void finalize_kernel(const float* __restrict__ gsum,
                                const float* __restrict__ gss,
                                const float* __restrict__ gamma,
                                const float* __restrict__ beta,
                                float* __restrict__ scale,
                                float* __restrict__ shift) {
    int c = threadIdx.x;
    const float inv_n = 1.0f / (float)N_NODES;
    float mean = gsum[c] * inv_n;
    float var = gss[c] * inv_n - mean * mean;
    float rs = rsqrtf(var + 1e-5f);
    float sc = gamma[c] * rs;
    scale[c] = sc;
    shift[c] = beta[c] - mean * sc;
}

__global__ __launch_bounds__(256) void norm_kernel(float* __restrict__ h,
                                                   const float* __restrict__ scale,
                                                   const float* __restrict__ shift) {
    size_t tid = (size_t)blockIdx.x * 256 + threadIdx.x;
    size_t e = tid * 4;
    if (e >= (size_t)N_NODES * D) return;
    int c = (int)(e & 127);
    float4 v = *(float4*)(h + e);
    v.x = fmaxf(v.x * scale[c + 0] + shift[c + 0], 0.f);
    v.y = fmaxf(v.y * scale[c + 1] + shift[c + 1], 0.f);
    v.z = fmaxf(v.z * scale[c + 2] + shift[c + 2], 0.f);
    v.w = fmaxf(v.w * scale[c + 3] + shift[c + 3], 0.f);
    *(float4*)(h + e) = v;
}

extern "C" void kernel_launch(void* const* d_in, const int* in_sizes, int n_in,
                              void* d_out, int out_size, void* d_ws, size_t ws_size,
                              hipStream_t stream) {
    const float* x     = (const float*)d_in[0];
    const int*   ei    = (const int*)d_in[1];
    const float* Wroot = (const float*)d_in[2];
    const float* Wrel  = (const float*)d_in[3];
    const float* brel  = (const float*)d_in[4];
    const float* gamma = (const float*)d_in[5];
    const float* beta  = (const float*)d_in[6];
    float* out = (float*)d_out;

    // workspace layout
    float* aggr  = (float*)d_ws;                       // N*D floats
    float* gsum  = aggr + (size_t)N_NODES * D;         // 128
    float* gss   = gsum + 128;                         // 128
    float* scale = gss + 128;                          // 128
    float* shift = scale + 128;                        // 128
    int* count    = (int*)(shift + 128);               // SCAN_TOT + slack (zeroed)
    int* rowstart = count + (SCAN_TOT + 256);          // N_NODES+1 (+slack)
    int* cursor   = rowstart + (SCAN_TOT + 256);       // N_NODES
    int* bsum     = cursor + N_NODES;                  // SCAN_BLOCKS (+slack)
    int* srcs     = bsum + 512;                        // N_EDGES

    // zero gsum/gss/scale/shift + count array in one shot
    hipMemsetAsync(gsum, 0, (512 + SCAN_TOT + 256) * sizeof(int), stream);

    hist_kernel<<<(N_EDGES + 255) / 256, 256, 0, stream>>>(ei, count);
    scan_partial<<<SCAN_BLOCKS, 256, 0, stream>>>(count, bsum);
    scan_bsum<<<1, 64, 0, stream>>>(bsum);
    scan_final<<<SCAN_BLOCKS, 256, 0, stream>>>(count, bsum, rowstart, cursor);
    bucket_kernel<<<(N_EDGES + 255) / 256, 256, 0, stream>>>(ei, cursor, srcs);
    gather_kernel<<<N_NODES / 4, 256, 0, stream>>>(x, rowstart, srcs, aggr);
    gemm_kernel<<<(N_NODES + 127) / 128, 256, 0, stream>>>(aggr, x, Wrel, Wroot, brel, out);
    stats_kernel<<<256, 256, 0, stream>>>(out, gsum, gss);
    finalize_kernel<<<1, 128, 0, stream>>>(gsum, gss, gamma, beta, scale, shift);
    norm_kernel<<<12500, 256, 0, stream>>>(out, scale, shift);
}

// Round 3
// 433.781 us; speedup vs baseline: 6.8237x; 1.3870x over previous
//
#include <hip/hip_runtime.h>

#define N_NODES 100000
#define N_EDGES 1600000
#define D 128
#define SCAN_BLOCKS 392                  // 392*256 = 100352 >= N_NODES+1
#define SCAN_TOT (SCAN_BLOCKS * 256)

typedef __bf16 bf16x8 __attribute__((ext_vector_type(8)));
typedef float f32x4 __attribute__((ext_vector_type(4)));

__device__ __forceinline__ unsigned f2bf(float f) {
    unsigned u = __float_as_uint(f);
    return (u + 0x7fffu + ((u >> 16) & 1u)) >> 16;   // RNE
}
__device__ __forceinline__ float bf_lo(unsigned u) { return __uint_as_float(u << 16); }
__device__ __forceinline__ float bf_hi(unsigned u) { return __uint_as_float(u & 0xffff0000u); }

// ---------------- convert x -> bf16 ----------------
__global__ __launch_bounds__(256) void cvt_x_kernel(const float* __restrict__ x,
                                                    unsigned short* __restrict__ x_bf) {
    size_t i = ((size_t)blockIdx.x * 256 + threadIdx.x) * 4;
    if (i >= (size_t)N_NODES * D) return;
    float4 v = *(const float4*)(x + i);
    uint2 p;
    p.x = f2bf(v.x) | (f2bf(v.y) << 16);
    p.y = f2bf(v.z) | (f2bf(v.w) << 16);
    *(uint2*)(x_bf + i) = p;
}

// ---------------- build Wt[c][k] bf16: k<128 -> W_rel[k][c], else W_root ----------------
__global__ __launch_bounds__(256) void cvt_w_kernel(const float* __restrict__ Wrel,
                                                    const float* __restrict__ Wroot,
                                                    unsigned short* __restrict__ Wt) {
    int c = blockIdx.x;          // 0..127
    int k = threadIdx.x;         // 0..255
    float v = (k < 128) ? Wrel[k * D + c] : Wroot[(k - 128) * D + c];
    Wt[c * 256 + k] = (unsigned short)f2bf(v);
}

// ---------------- CSR build ----------------
__global__ __launch_bounds__(256) void hist_kernel(const int* __restrict__ ei,
                                                   int* __restrict__ count) {
    int e = blockIdx.x * 256 + threadIdx.x;
    if (e < N_EDGES) atomicAdd(&count[ei[N_EDGES + e]], 1);
}

__global__ __launch_bounds__(256) void scan_partial(const int* __restrict__ count,
                                                    int* __restrict__ bsum) {
    int t = threadIdx.x;
    int i = blockIdx.x * 256 + t;
    __shared__ int red[256];
    red[t] = count[i];
    __syncthreads();
    for (int off = 128; off > 0; off >>= 1) {
        if (t < off) red[t] += red[t + off];
        __syncthreads();
    }
    if (t == 0) bsum[blockIdx.x] = red[0];
}

// parallel exclusive scan of the 392 block sums (one block, LDS)
__global__ __launch_bounds__(512) void scan_bsum(int* __restrict__ bsum) {
    __shared__ int s[512];
    int t = threadIdx.x;
    int v = (t < SCAN_BLOCKS) ? bsum[t] : 0;
    s[t] = v;
    __syncthreads();
    for (int off = 1; off < 512; off <<= 1) {
        int a = (t >= off) ? s[t - off] : 0;
        __syncthreads();
        s[t] += a;
        __syncthreads();
    }
    if (t < SCAN_BLOCKS) bsum[t] = s[t] - v;
}

__global__ __launch_bounds__(256) void scan_final(const int* __restrict__ count,
                                                  const int* __restrict__ bsum,
                                                  int* __restrict__ rowstart,
                                                  int* __restrict__ cursor) {
    int t = threadIdx.x;
    int i = blockIdx.x * 256 + t;
    __shared__ int red[256];
    int v = count[i];
    red[t] = v;
    __syncthreads();
    for (int off = 1; off < 256; off <<= 1) {
        int a = (t >= off) ? red[t - off] : 0;
        __syncthreads();
        red[t] += a;
        __syncthreads();
    }
    int excl = red[t] - v + bsum[blockIdx.x];
    if (i <= N_NODES) rowstart[i] = excl;
    if (i < N_NODES) cursor[i] = excl;
}

__global__ __launch_bounds__(256) void bucket_kernel(const int* __restrict__ ei,
                                                     int* __restrict__ cursor,
                                                     int* __restrict__ srcs) {
    int e = blockIdx.x * 256 + threadIdx.x;
    if (e < N_EDGES) {
        int dst = ei[N_EDGES + e];
        int src = ei[e];
        int pos = atomicAdd(&cursor[dst], 1);
        srcs[pos] = src;
    }
}

// ---------------- gather (bf16): aggr_bf[n] = sum x_bf[srcs[e]] ----------------
// 64 lanes per node, 2 channels (1 uint) per lane, fp32 accumulate
__global__ __launch_bounds__(256) void gather_kernel(const unsigned short* __restrict__ x_bf,
                                                     const int* __restrict__ rowstart,
                                                     const int* __restrict__ srcs,
                                                     unsigned short* __restrict__ aggr_bf) {
    int t = threadIdx.x;
    int node = blockIdx.x * 4 + (t >> 6);
    int lane = t & 63;
    int begin = rowstart[node];
    int end = rowstart[node + 1];
    const unsigned short* xp = x_bf + lane * 2;
    float ax = 0.f, ay = 0.f;
    int e = begin;
    for (; e + 3 < end; e += 4) {
        int s0 = srcs[e], s1 = srcs[e + 1], s2 = srcs[e + 2], s3 = srcs[e + 3];
        unsigned u0 = *(const unsigned*)(xp + (size_t)s0 * D);
        unsigned u1 = *(const unsigned*)(xp + (size_t)s1 * D);
        unsigned u2 = *(const unsigned*)(xp + (size_t)s2 * D);
        unsigned u3 = *(const unsigned*)(xp + (size_t)s3 * D);
        ax += bf_lo(u0) + bf_lo(u1) + bf_lo(u2) + bf_lo(u3);
        ay += bf_hi(u0) + bf_hi(u1) + bf_hi(u2) + bf_hi(u3);
    }
    for (; e < end; ++e) {
        unsigned u = *(const unsigned*)(xp + (size_t)srcs[e] * D);
        ax += bf_lo(u);
        ay += bf_hi(u);
    }
    *(unsigned*)(aggr_bf + (size_t)node * D + lane * 2) = f2bf(ax) | (f2bf(ay) << 16);
}

// ---------------- MFMA GEMM + fused BN stats ----------------
// out[128 rows x 128 cols per block] = [aggr_bf | x_bf] @ Wt^T + brel
// 256 threads = 4 waves; wave handles 32 rows x 128 cols; 16x16x32 bf16 MFMA.
#define LDSTRIDE 40   // 32 k + 8 pad (80 B rows: 16B-aligned, 2-way conflicts only)
__global__ __launch_bounds__(256) void gemm_mfma(const unsigned short* __restrict__ aggr_bf,
                                                 const unsigned short* __restrict__ x_bf,
                                                 const unsigned short* __restrict__ Wt,
                                                 const float* __restrict__ brel,
                                                 float* __restrict__ out,
                                                 float* __restrict__ gsum,
                                                 float* __restrict__ gss) {
    __shared__ unsigned short As[128][LDSTRIDE];
    __shared__ unsigned short Bs[128][LDSTRIDE];
    __shared__ float sbias[128];
    __shared__ float SredS[4][128];
    __shared__ float SredQ[4][128];

    const int t = threadIdx.x;
    const int wave = t >> 6;
    const int lane = t & 63;
    const int quad = lane >> 4;
    const int l16 = lane & 15;
    const int blockRow = blockIdx.x * 128;

    if (t < 128) sbias[t] = brel[t];

    f32x4 acc[2][8];
#pragma unroll
    for (int i = 0; i < 2; ++i)
#pragma unroll
        for (int j = 0; j < 8; ++j) acc[i][j] = (f32x4){0.f, 0.f, 0.f, 0.f};

    for (int kc = 0; kc < 8; ++kc) {
        const unsigned short* Asrc = (kc < 4) ? aggr_bf : x_bf;
        const int k0 = (kc & 3) * 32;
        // stage A: 128 rows x 32 k (16 B per thread x 2)
#pragma unroll
        for (int s = t; s < 512; s += 256) {
            int row = s >> 2;
            int q = (s & 3) * 8;
            int grow = blockRow + row;
            uint4 v = make_uint4(0, 0, 0, 0);
            if (grow < N_NODES) v = *(const uint4*)(Asrc + (size_t)grow * D + k0 + q);
            *(uint4*)&As[row][q] = v;
        }
        // stage B: 128 cols x 32 k from Wt[c][256]
#pragma unroll
        for (int s = t; s < 512; s += 256) {
            int col = s >> 2;
            int q = (s & 3) * 8;
            uint4 v = *(const uint4*)(Wt + col * 256 + kc * 32 + q);
            *(uint4*)&Bs[col][q] = v;
        }
        __syncthreads();

        bf16x8 afrag0 = *(bf16x8*)&As[wave * 32 + l16][quad * 8];
        bf16x8 afrag1 = *(bf16x8*)&As[wave * 32 + 16 + l16][quad * 8];
#pragma unroll
        for (int ct = 0; ct < 8; ++ct) {
            bf16x8 bfrag = *(bf16x8*)&Bs[ct * 16 + l16][quad * 8];
            acc[0][ct] = __builtin_amdgcn_mfma_f32_16x16x32_bf16(afrag0, bfrag, acc[0][ct], 0, 0, 0);
            acc[1][ct] = __builtin_amdgcn_mfma_f32_16x16x32_bf16(afrag1, bfrag, acc[1][ct], 0, 0, 0);
        }
        __syncthreads();
    }

    // epilogue: bias, store, per-column sum/sumsq
    float csum[8], css[8];
#pragma unroll
    for (int ct = 0; ct < 8; ++ct) { csum[ct] = 0.f; css[ct] = 0.f; }

#pragma unroll
    for (int rt = 0; rt < 2; ++rt) {
#pragma unroll
        for (int ct = 0; ct < 8; ++ct) {
            int col = ct * 16 + l16;
            float b = sbias[col];
#pragma unroll
            for (int reg = 0; reg < 4; ++reg) {
                int row = blockRow + wave * 32 + rt * 16 + quad * 4 + reg;
                if (row < N_NODES) {
                    float v = acc[rt][ct][reg] + b;
                    out[(size_t)row * D + col] = v;
                    csum[ct] += v;
                    css[ct] += v * v;
                }
            }
        }
    }
    // reduce across quads (rows) via shfl, then across waves via LDS
#pragma unroll
    for (int ct = 0; ct < 8; ++ct) {
        float s = csum[ct], q = css[ct];
        s += __shfl_xor(s, 16);
        s += __shfl_xor(s, 32);
        q += __shfl_xor(q, 16);
        q += __shfl_xor(q, 32);
        if (quad == 0) {
            SredS[wave][ct * 16 + l16] = s;
            SredQ[wave][ct * 16 + l16] = q;
        }
    }
    __syncthreads();
    if (t < 128) {
        float s = SredS[0][t] + SredS[1][t] + SredS[2][t] + SredS[3][t];
        float q = SredQ[0][t] + SredQ[1][t] + SredQ[2][t] + SredQ[3][t];
        unsafeAtomicAdd(&gsum[t], s);
        unsafeAtomicAdd(&gss[t], q);
    }
}

__global__ void finalize_kernel(const float* __restrict__ gsum,
                                const float* __restrict__ gss,
                                const float* __restrict__ gamma,
                                const float* __restrict__ beta,
                                float* __restrict__ scale,
                                float* __restrict__ shift) {
    int c = threadIdx.x;
    const float inv_n = 1.0f / (float)N_NODES;
    float mean = gsum[c] * inv_n;
    float var = gss[c] * inv_n - mean * mean;
    float rs = rsqrtf(var + 1e-5f);
    float sc = gamma[c] * rs;
    scale[c] = sc;
    shift[c] = beta[c] - mean * sc;
}

__global__ __launch_bounds__(256) void norm_kernel(float* __restrict__ h,
                                                   const float* __restrict__ scale,
                                                   const float* __restrict__ shift) {
    size_t tid = (size_t)blockIdx.x * 256 + threadIdx.x;
    size_t e = tid * 4;
    if (e >= (size_t)N_NODES * D) return;
    int c = (int)(e & 127);
    float4 v = *(float4*)(h + e);
    v.x = fmaxf(v.x * scale[c + 0] + shift[c + 0], 0.f);
    v.y = fmaxf(v.y * scale[c + 1] + shift[c + 1], 0.f);
    v.z = fmaxf(v.z * scale[c + 2] + shift[c + 2], 0.f);
    v.w = fmaxf(v.w * scale[c + 3] + shift[c + 3], 0.f);
    *(float4*)(h + e) = v;
}

extern "C" void kernel_launch(void* const* d_in, const int* in_sizes, int n_in,
                              void* d_out, int out_size, void* d_ws, size_t ws_size,
                              hipStream_t stream) {
    const float* x     = (const float*)d_in[0];
    const int*   ei    = (const int*)d_in[1];
    const float* Wroot = (const float*)d_in[2];
    const float* Wrel  = (const float*)d_in[3];
    const float* brel  = (const float*)d_in[4];
    const float* gamma = (const float*)d_in[5];
    const float* beta  = (const float*)d_in[6];
    float* out = (float*)d_out;

    // workspace layout
    unsigned short* aggr_bf = (unsigned short*)d_ws;            // N*D
    unsigned short* x_bf    = aggr_bf + (size_t)N_NODES * D;    // N*D
    unsigned short* Wt      = x_bf + (size_t)N_NODES * D;       // 128*256
    float* gsum  = (float*)(Wt + 128 * 256);                    // 128
    float* gss   = gsum + 128;
    float* scale = gss + 128;
    float* shift = scale + 128;
    int* count    = (int*)(shift + 128);                        // SCAN_TOT+256 (zeroed)
    int* rowstart = count + (SCAN_TOT + 256);                   // N_NODES+1 (+slack)
    int* cursor   = rowstart + (SCAN_TOT + 256);                // N_NODES
    int* bsum     = cursor + N_NODES;                           // SCAN_BLOCKS (+slack)
    int* srcs     = bsum + 512;                                 // N_EDGES

    // zero gsum/gss/scale/shift + count in one shot (contiguous)
    hipMemsetAsync(gsum, 0, (512 + SCAN_TOT + 256) * sizeof(int), stream);

    cvt_x_kernel<<<(N_NODES * D / 4 + 255) / 256, 256, 0, stream>>>(x, x_bf);
    cvt_w_kernel<<<128, 256, 0, stream>>>(Wrel, Wroot, Wt);
    hist_kernel<<<(N_EDGES + 255) / 256, 256, 0, stream>>>(ei, count);
    scan_partial<<<SCAN_BLOCKS, 256, 0, stream>>>(count, bsum);
    scan_bsum<<<1, 512, 0, stream>>>(bsum);
    scan_final<<<SCAN_BLOCKS, 256, 0, stream>>>(count, bsum, rowstart, cursor);
    bucket_kernel<<<(N_EDGES + 255) / 256, 256, 0, stream>>>(ei, cursor, srcs);
    gather_kernel<<<N_NODES / 4, 256, 0, stream>>>(x_bf, rowstart, srcs, aggr_bf);
    gemm_mfma<<<(N_NODES + 127) / 128, 256, 0, stream>>>(aggr_bf, x_bf, Wt, brel, out, gsum, gss);
    finalize_kernel<<<1, 128, 0, stream>>>(gsum, gss, gamma, beta, scale, shift);
    norm_kernel<<<12500, 256, 0, stream>>>(out, scale, shift);
}

// Round 4
// 315.756 us; speedup vs baseline: 9.3743x; 1.3738x over previous
//
#include <hip/hip_runtime.h>

#define N_NODES 100000
#define N_EDGES 1600000
#define D 128
#define NB 196              // buckets of 512 nodes: 196*512 = 100352 >= N_NODES
#define EPT 10              // edges per thread in binning
#define CHUNK 2560          // 256 threads * EPT
#define BIN_BLOCKS 625      // 625 * 2560 = 1,600,000 exactly

typedef __bf16 bf16x8 __attribute__((ext_vector_type(8)));
typedef float f32x4 __attribute__((ext_vector_type(4)));

__device__ __forceinline__ unsigned f2bf(float f) {
    unsigned u = __float_as_uint(f);
    return (u + 0x7fffu + ((u >> 16) & 1u)) >> 16;   // RNE
}
__device__ __forceinline__ float bf_lo(unsigned u) { return __uint_as_float(u << 16); }
__device__ __forceinline__ float bf_hi(unsigned u) { return __uint_as_float(u & 0xffff0000u); }

// ---------------- convert x -> bf16 ----------------
__global__ __launch_bounds__(256) void cvt_x_kernel(const float* __restrict__ x,
                                                    unsigned short* __restrict__ x_bf) {
    size_t i = ((size_t)blockIdx.x * 256 + threadIdx.x) * 4;
    if (i >= (size_t)N_NODES * D) return;
    float4 v = *(const float4*)(x + i);
    uint2 p;
    p.x = f2bf(v.x) | (f2bf(v.y) << 16);
    p.y = f2bf(v.z) | (f2bf(v.w) << 16);
    *(uint2*)(x_bf + i) = p;
}

// ---------------- build Wt[c][k] bf16 ----------------
__global__ __launch_bounds__(256) void cvt_w_kernel(const float* __restrict__ Wrel,
                                                    const float* __restrict__ Wroot,
                                                    unsigned short* __restrict__ Wt) {
    int c = blockIdx.x;
    int k = threadIdx.x;
    float v = (k < 128) ? Wrel[k * D + c] : Wroot[(k - 128) * D + c];
    Wt[c * 256 + k] = (unsigned short)f2bf(v);
}

// ---------------- bucket histogram (196 buckets, LDS-aggregated) ----------------
__global__ __launch_bounds__(256) void bhist_kernel(const int* __restrict__ ei,
                                                    int* __restrict__ bcount) {
    __shared__ int h[256];
    int t = threadIdx.x;
    h[t] = 0;
    __syncthreads();
    int base = blockIdx.x * CHUNK;
#pragma unroll
    for (int i = 0; i < EPT; ++i) {
        int dst = ei[N_EDGES + base + i * 256 + t];
        atomicAdd(&h[dst >> 9], 1);
    }
    __syncthreads();
    if (t < NB && h[t]) atomicAdd(&bcount[t], h[t]);
}

// ---------------- bucket scan (1 block) ----------------
__global__ __launch_bounds__(256) void bscan_kernel(const int* __restrict__ bcount,
                                                    int* __restrict__ bucket_base,
                                                    int* __restrict__ bcur) {
    __shared__ int s[256];
    int t = threadIdx.x;
    int v = (t < NB) ? bcount[t] : 0;
    s[t] = v;
    __syncthreads();
    for (int off = 1; off < 256; off <<= 1) {
        int a = (t >= off) ? s[t - off] : 0;
        __syncthreads();
        s[t] += a;
        __syncthreads();
    }
    int excl = s[t] - v;
    if (t < NB) {
        bucket_base[t] = excl;
        bcur[t] = excl;
    }
    if (t == NB) bucket_base[NB] = N_EDGES;
}

// ---------------- binify: block-local multisplit, coalesced pair writes ----------------
__global__ __launch_bounds__(256) void binify_kernel(const int* __restrict__ ei,
                                                     int* __restrict__ bcur,
                                                     uint2* __restrict__ pairs) {
    __shared__ int lhist[256];
    __shared__ int lstart[256];
    __shared__ int lfill[256];
    __shared__ int gbase[256];
    __shared__ uint2 stage[CHUNK];   // 20 KB

    int t = threadIdx.x;
    int base = blockIdx.x * CHUNK;
    lhist[t] = 0;
    lfill[t] = 0;
    __syncthreads();

    int src[EPT], dst[EPT];
#pragma unroll
    for (int i = 0; i < EPT; ++i) {
        int e = base + i * 256 + t;
        src[i] = ei[e];
        dst[i] = ei[N_EDGES + e];
        atomicAdd(&lhist[dst[i] >> 9], 1);
    }
    __syncthreads();

    // exclusive scan of lhist
    int v = lhist[t];
    lstart[t] = v;
    __syncthreads();
    for (int off = 1; off < 256; off <<= 1) {
        int a = (t >= off) ? lstart[t - off] : 0;
        __syncthreads();
        lstart[t] += a;
        __syncthreads();
    }
    int excl = lstart[t] - v;
    if (t < NB && v > 0) gbase[t] = atomicAdd(&bcur[t], v);
    __syncthreads();
    lstart[t] = excl;
    __syncthreads();

    // stable local reorder into stage
#pragma unroll
    for (int i = 0; i < EPT; ++i) {
        int b = dst[i] >> 9;
        int lp = atomicAdd(&lfill[b], 1);
        stage[lstart[b] + lp] = make_uint2((unsigned)src[i], (unsigned)dst[i]);
    }
    __syncthreads();

    // segmented-coalesced global write
    for (int i = t; i < CHUNK; i += 256) {
        uint2 p = stage[i];
        int b = (int)(p.y >> 9);
        pairs[gbase[b] + (i - lstart[b])] = p;
    }
}

// ---------------- place: per-bucket local count+scan -> rowstart, srcs ----------------
__global__ __launch_bounds__(256) void place_kernel(const uint2* __restrict__ pairs,
                                                    const int* __restrict__ bucket_base,
                                                    int* __restrict__ rowstart,
                                                    int* __restrict__ srcs) {
    __shared__ int bufA[512];
    __shared__ int bufB[512];
    int b = blockIdx.x;
    int t = threadIdx.x;
    int pbeg = bucket_base[b];
    int pend = bucket_base[b + 1];

    bufA[t] = 0;
    bufA[t + 256] = 0;
    __syncthreads();
    for (int i = pbeg + t; i < pend; i += 256)
        atomicAdd(&bufA[pairs[i].y & 511], 1);
    __syncthreads();

    // exclusive scan of 512 counts (seed-shift + Hillis-Steele ping-pong)
    for (int j = t; j < 512; j += 256) bufB[j] = j ? bufA[j - 1] : 0;
    __syncthreads();
    int* cur = bufB;
    int* nxt = bufA;
    for (int off = 1; off < 512; off <<= 1) {
        for (int j = t; j < 512; j += 256)
            nxt[j] = cur[j] + ((j >= off) ? cur[j - off] : 0);
        __syncthreads();
        int* tmp = cur; cur = nxt; nxt = tmp;
    }

    // rowstart + LDS cursors (absolute srcs positions)
    for (int j = t; j < 512; j += 256) {
        int gnode = (b << 9) + j;
        int val = pbeg + cur[j];
        if (gnode <= N_NODES) rowstart[gnode] = val;
        nxt[j] = val;
    }
    __syncthreads();

    // place: all writes in block-exclusive srcs window
    for (int i = pbeg + t; i < pend; i += 256) {
        uint2 p = pairs[i];
        int pos = atomicAdd(&nxt[p.y & 511], 1);
        srcs[pos] = (int)p.x;
    }
}

// ---------------- gather (bf16) ----------------
__global__ __launch_bounds__(256) void gather_kernel(const unsigned short* __restrict__ x_bf,
                                                     const int* __restrict__ rowstart,
                                                     const int* __restrict__ srcs,
                                                     unsigned short* __restrict__ aggr_bf) {
    int t = threadIdx.x;
    int node = blockIdx.x * 4 + (t >> 6);
    int lane = t & 63;
    int begin = rowstart[node];
    int end = rowstart[node + 1];
    const unsigned short* xp = x_bf + lane * 2;
    float ax = 0.f, ay = 0.f;
    int e = begin;
    for (; e + 3 < end; e += 4) {
        int s0 = srcs[e], s1 = srcs[e + 1], s2 = srcs[e + 2], s3 = srcs[e + 3];
        unsigned u0 = *(const unsigned*)(xp + (size_t)s0 * D);
        unsigned u1 = *(const unsigned*)(xp + (size_t)s1 * D);
        unsigned u2 = *(const unsigned*)(xp + (size_t)s2 * D);
        unsigned u3 = *(const unsigned*)(xp + (size_t)s3 * D);
        ax += bf_lo(u0) + bf_lo(u1) + bf_lo(u2) + bf_lo(u3);
        ay += bf_hi(u0) + bf_hi(u1) + bf_hi(u2) + bf_hi(u3);
    }
    for (; e < end; ++e) {
        unsigned u = *(const unsigned*)(xp + (size_t)srcs[e] * D);
        ax += bf_lo(u);
        ay += bf_hi(u);
    }
    *(unsigned*)(aggr_bf + (size_t)node * D + lane * 2) = f2bf(ax) | (f2bf(ay) << 16);
}

// ---------------- MFMA GEMM + fused BN stats ----------------
#define LDSTRIDE 40
__global__ __launch_bounds__(256) void gemm_mfma(const unsigned short* __restrict__ aggr_bf,
                                                 const unsigned short* __restrict__ x_bf,
                                                 const unsigned short* __restrict__ Wt,
                                                 const float* __restrict__ brel,
                                                 float* __restrict__ out,
                                                 float* __restrict__ gsum,
                                                 float* __restrict__ gss) {
    __shared__ unsigned short As[128][LDSTRIDE];
    __shared__ unsigned short Bs[128][LDSTRIDE];
    __shared__ float sbias[128];
    __shared__ float SredS[4][128];
    __shared__ float SredQ[4][128];

    const int t = threadIdx.x;
    const int wave = t >> 6;
    const int lane = t & 63;
    const int quad = lane >> 4;
    const int l16 = lane & 15;
    const int blockRow = blockIdx.x * 128;

    if (t < 128) sbias[t] = brel[t];

    f32x4 acc[2][8];
#pragma unroll
    for (int i = 0; i < 2; ++i)
#pragma unroll
        for (int j = 0; j < 8; ++j) acc[i][j] = (f32x4){0.f, 0.f, 0.f, 0.f};

    for (int kc = 0; kc < 8; ++kc) {
        const unsigned short* Asrc = (kc < 4) ? aggr_bf : x_bf;
        const int k0 = (kc & 3) * 32;
#pragma unroll
        for (int s = t; s < 512; s += 256) {
            int row = s >> 2;
            int q = (s & 3) * 8;
            int grow = blockRow + row;
            uint4 v = make_uint4(0, 0, 0, 0);
            if (grow < N_NODES) v = *(const uint4*)(Asrc + (size_t)grow * D + k0 + q);
            *(uint4*)&As[row][q] = v;
        }
#pragma unroll
        for (int s = t; s < 512; s += 256) {
            int col = s >> 2;
            int q = (s & 3) * 8;
            uint4 v = *(const uint4*)(Wt + col * 256 + kc * 32 + q);
            *(uint4*)&Bs[col][q] = v;
        }
        __syncthreads();

        bf16x8 afrag0 = *(bf16x8*)&As[wave * 32 + l16][quad * 8];
        bf16x8 afrag1 = *(bf16x8*)&As[wave * 32 + 16 + l16][quad * 8];
#pragma unroll
        for (int ct = 0; ct < 8; ++ct) {
            bf16x8 bfrag = *(bf16x8*)&Bs[ct * 16 + l16][quad * 8];
            acc[0][ct] = __builtin_amdgcn_mfma_f32_16x16x32_bf16(afrag0, bfrag, acc[0][ct], 0, 0, 0);
            acc[1][ct] = __builtin_amdgcn_mfma_f32_16x16x32_bf16(afrag1, bfrag, acc[1][ct], 0, 0, 0);
        }
        __syncthreads();
    }

    float csum[8], css[8];
#pragma unroll
    for (int ct = 0; ct < 8; ++ct) { csum[ct] = 0.f; css[ct] = 0.f; }

#pragma unroll
    for (int rt = 0; rt < 2; ++rt) {
#pragma unroll
        for (int ct = 0; ct < 8; ++ct) {
            int col = ct * 16 + l16;
            float bv = sbias[col];
#pragma unroll
            for (int reg = 0; reg < 4; ++reg) {
                int row = blockRow + wave * 32 + rt * 16 + quad * 4 + reg;
                if (row < N_NODES) {
                    float v = acc[rt][ct][reg] + bv;
                    out[(size_t)row * D + col] = v;
                    csum[ct] += v;
                    css[ct] += v * v;
                }
            }
        }
    }
#pragma unroll
    for (int ct = 0; ct < 8; ++ct) {
        float s = csum[ct], q = css[ct];
        s += __shfl_xor(s, 16);
        s += __shfl_xor(s, 32);
        q += __shfl_xor(q, 16);
        q += __shfl_xor(q, 32);
        if (quad == 0) {
            SredS[wave][ct * 16 + l16] = s;
            SredQ[wave][ct * 16 + l16] = q;
        }
    }
    __syncthreads();
    if (t < 128) {
        float s = SredS[0][t] + SredS[1][t] + SredS[2][t] + SredS[3][t];
        float q = SredQ[0][t] + SredQ[1][t] + SredQ[2][t] + SredQ[3][t];
        unsafeAtomicAdd(&gsum[t], s);
        unsafeAtomicAdd(&gss[t], q);
    }
}

__global__ void finalize_kernel(const float* __restrict__ gsum,
                                const float* __restrict__ gss,
                                const float* __restrict__ gamma,
                                const float* __restrict__ beta,
                                float* __restrict__ scale,
                                float* __restrict__ shift) {
    int c = threadIdx.x;
    const float inv_n = 1.0f / (float)N_NODES;
    float mean = gsum[c] * inv_n;
    float var = gss[c] * inv_n - mean * mean;
    float rs = rsqrtf(var + 1e-5f);
    float sc = gamma[c] * rs;
    scale[c] = sc;
    shift[c] = beta[c] - mean * sc;
}

__global__ __launch_bounds__(256) void norm_kernel(float* __restrict__ h,
                                                   const float* __restrict__ scale,
                                                   const float* __restrict__ shift) {
    size_t tid = (size_t)blockIdx.x * 256 + threadIdx.x;
    size_t e = tid * 4;
    if (e >= (size_t)N_NODES * D) return;
    int c = (int)(e & 127);
    float4 v = *(float4*)(h + e);
    v.x = fmaxf(v.x * scale[c + 0] + shift[c + 0], 0.f);
    v.y = fmaxf(v.y * scale[c + 1] + shift[c + 1], 0.f);
    v.z = fmaxf(v.z * scale[c + 2] + shift[c + 2], 0.f);
    v.w = fmaxf(v.w * scale[c + 3] + shift[c + 3], 0.f);
    *(float4*)(h + e) = v;
}

extern "C" void kernel_launch(void* const* d_in, const int* in_sizes, int n_in,
                              void* d_out, int out_size, void* d_ws, size_t ws_size,
                              hipStream_t stream) {
    const float* x     = (const float*)d_in[0];
    const int*   ei    = (const int*)d_in[1];
    const float* Wroot = (const float*)d_in[2];
    const float* Wrel  = (const float*)d_in[3];
    const float* brel  = (const float*)d_in[4];
    const float* gamma = (const float*)d_in[5];
    const float* beta  = (const float*)d_in[6];
    float* out = (float*)d_out;

    // workspace layout (all segments 8B-aligned)
    unsigned short* aggr_bf = (unsigned short*)d_ws;            // N*D
    unsigned short* x_bf    = aggr_bf + (size_t)N_NODES * D;    // N*D
    unsigned short* Wt      = x_bf + (size_t)N_NODES * D;       // 128*256
    float* gsum  = (float*)(Wt + 128 * 256);                    // 128 ─┐
    float* gss   = gsum + 128;                                  // 128  │ zeroed
    int* bcount  = (int*)(gss + 128);                           // 256 ─┘
    float* scale = (float*)(bcount + 256);                      // 128
    float* shift = scale + 128;                                 // 128
    int* bucket_base = (int*)(shift + 128);                     // 256 (197 used)
    int* bcur    = bucket_base + 256;                           // 256
    int* rowstart = bcur + 256;                                 // 100352
    uint2* pairs = (uint2*)(rowstart + 100352);                 // N_EDGES (12.8 MB)
    int* srcs    = (int*)(pairs + N_EDGES);                     // N_EDGES (6.4 MB)

    // zero gsum + gss + bcount (contiguous 512 words)
    hipMemsetAsync(gsum, 0, 512 * sizeof(int), stream);

    cvt_x_kernel<<<(N_NODES * D / 4 + 255) / 256, 256, 0, stream>>>(x, x_bf);
    cvt_w_kernel<<<128, 256, 0, stream>>>(Wrel, Wroot, Wt);
    bhist_kernel<<<BIN_BLOCKS, 256, 0, stream>>>(ei, bcount);
    bscan_kernel<<<1, 256, 0, stream>>>(bcount, bucket_base, bcur);
    binify_kernel<<<BIN_BLOCKS, 256, 0, stream>>>(ei, bcur, pairs);
    place_kernel<<<NB, 256, 0, stream>>>(pairs, bucket_base, rowstart, srcs);
    gather_kernel<<<N_NODES / 4, 256, 0, stream>>>(x_bf, rowstart, srcs, aggr_bf);
    gemm_mfma<<<(N_NODES + 127) / 128, 256, 0, stream>>>(aggr_bf, x_bf, Wt, brel, out, gsum, gss);
    finalize_kernel<<<1, 128, 0, stream>>>(gsum, gss, gamma, beta, scale, shift);
    norm_kernel<<<12500, 256, 0, stream>>>(out, scale, shift);
}